// Round 4
// baseline (123.724 us; speedup 1.0000x reference)
//
#include <hip/hip_runtime.h>

#define HH 50
#define WW 50
#define EPSF 1e-8f

// Histogram: x (birth) in [0,1] -> 128 bins; y (pers) in [-0.5, 1.0] -> 96 bins.
// Nearest-bin splat (1 LDS atomic/point). p < -0.5 dropped: gy <= exp(-12.5).
// R3: K3 fused into K2 as a ticket-epilogue (last-done block computes img in
//     LDS, register-blocked dot, max+normalize+store). 2 dispatches total.
#define BXH 128
#define BYH 96
#define Y0F (-0.5f)
#define YSPAN 1.5f
#define REPSZ (BXH * BYH)            // 12288 bins; LDS 48 KB; bf16 replica 24 KB

// ws float offsets (layout kept identical to R2)
#define GXOFF 0                       // gx_tab[w][ix] : 50*128 = 6400
#define GYOFF (GXOFF + WW * BXH)      // gy_tab[h][iy] : 50*96  = 4800
#define POFF  (GYOFF + HH * BYH)      // P[iy][w]      : 96*50  = 4800
#define IMGOFF (POFF + BYH * WW)      // (img slot retained for layout only)
#define CNTOFF (IMGOFF + HH * WW + 12) // int ticket counter (padded)
#define REPOFF (CNTOFF + 4)           // byte offset REPOFF*4 is 16B-aligned
// check: REPOFF = 6400+4800+4800+2500+12+4 = 18516; *4 = 74064 = 16*4629  ok

__device__ __forceinline__ unsigned bf16pk(float a, float b) {
    unsigned ua = __float_as_uint(a), ub = __float_as_uint(b);
    ua = (ua + 0x7FFFu + ((ua >> 16) & 1u)) >> 16;       // RNE
    ub = (ub + 0x7FFFu + ((ub >> 16) & 1u)) >> 16;
    return ua | (ub << 16);
}

__device__ __forceinline__ void splat1(float b, float death, float* hist) {
    const float p = death - b;               // pers == weight (may be negative)
    if (p < Y0F) return;
    int ix = (int)(b * (float)BXH);          // b >= 0: trunc == floor
    int iy = (int)((p - Y0F) * 64.0f);       // BYH/YSPAN = 96/1.5 = 64 exact
    ix = min(ix, BXH - 1);
    iy = min(iy, BYH - 1);
    atomicAdd(&hist[iy * BXH + ix], p);
}

// ---------------------------------------------------------------------------
// K1: per-block private LDS histogram (nearest splat), dump replica as bf16.
// Block 0 additionally builds the exp lookup tables + zeroes the K2 ticket.
// NOTE (prev session lesson): do NOT fuse stages behind an intra-kernel spin
// barrier — blocks polling one atomic line starved the ticket path. The
// ticket-epilogue below never waits: only the last block proceeds.
// ---------------------------------------------------------------------------
__global__ __launch_bounds__(1024) void pie_hist_lds(
    const float4* __restrict__ pairs4, int n,
    const float* __restrict__ grid_x, const float* __restrict__ grid_y,
    const float* __restrict__ sigma_p, float* __restrict__ ws, int R)
{
    __shared__ float hist[REPSZ];            // 48 KB
    const int t = threadIdx.x;

    {   // vectorized LDS zero (ds_write_b128): 12288/4/1024 = 3 iters
        const float4 z = make_float4(0.f, 0.f, 0.f, 0.f);
        float4* h4 = (float4*)hist;
        #pragma unroll
        for (int i = t; i < REPSZ / 4; i += 1024) h4[i] = z;
    }

    if (blockIdx.x == 0) {
        if (t == 0) ((int*)ws)[CNTOFF] = 0;  // ticket
        const float s = *sigma_p;
        const float a = 1.0f / (2.0f * s * s);
        for (int i = t; i < WW * BXH; i += 1024) {
            const int w = i >> 7, ix = i & (BXH - 1);
            const float c = (ix + 0.5f) * (1.0f / BXH);
            const float d = grid_x[w] - c;
            ws[GXOFF + i] = __expf(-d * d * a);
        }
        for (int i = t; i < HH * BYH; i += 1024) {
            const int h = i / BYH, iy = i - h * BYH;
            const float c = Y0F + (iy + 0.5f) * (YSPAN / (float)BYH);
            const float d = grid_y[h] - c;
            ws[GYOFF + i] = __expf(-d * d * a);
        }
    }
    __syncthreads();

    const int n2 = n >> 1;                   // two points per float4
    const int stride = R * 1024;
    #pragma unroll 4
    for (int i = blockIdx.x * 1024 + t; i < n2; i += stride) {
        const float4 q = pairs4[i];
        splat1(q.x, q.y, hist);
        splat1(q.z, q.w, hist);
    }
    if ((n & 1) && blockIdx.x == 0 && t == 0) {
        const float2 last = ((const float2*)pairs4)[n - 1];
        splat1(last.x, last.y, hist);
    }
    __syncthreads();

    // dump as bf16: 2x ds_read_b128 -> 1x global_store_dwordx4 (8 bins/iter)
    uint4* dst = (uint4*)((char*)ws + (size_t)REPOFF * 4 + (size_t)blockIdx.x * (REPSZ * 2));
    const float4* src = (const float4*)hist;
    #pragma unroll
    for (int i = t; i < REPSZ / 8; i += 1024) {
        const float4 a = src[2 * i], b = src[2 * i + 1];
        uint4 o;
        o.x = bf16pk(a.x, a.y); o.y = bf16pk(a.z, a.w);
        o.z = bf16pk(b.x, b.y); o.w = bf16pk(b.z, b.w);
        dst[i] = o;
    }
}

// ---------------------------------------------------------------------------
// K2 (fused): one block per y-row. Merge R bf16 replicas for this row
// (64 groups x 16 uint4 slots; R=256 -> exactly 4 loads/group), reduce,
// P[row][w] = sum_ix row[ix] * gx_tab[w][ix], write P, take ticket.
// Last-done block: img = gy x P fully in LDS, register-blocked dot
// (800 thr = 50 w x 16 r-chunks, 6 P vals in regs, shfl_xor reduce),
// then max + normalize + store out. No block ever waits.
// ---------------------------------------------------------------------------
__global__ __launch_bounds__(1024) void pie_c1(float* __restrict__ ws,
                                               float* __restrict__ out, int R)
{
    __shared__ float part[64 * BXH];         // 32 KB
    __shared__ float row[BXH];
    __shared__ float gxl[WW * (BXH + 1)];    // stride 129: conflict-free dot
    __shared__ float Pl[BYH * WW];           // 18.75 KB (epilogue)
    __shared__ float gyl[HH * BYH];          // 18.75 KB (epilogue)
    __shared__ float imgl[HH * WW];          // 10 KB (epilogue)
    __shared__ float redmax[16];
    __shared__ int is_last;
    const int t = threadIdx.x;
    const int rowi = blockIdx.x;

    for (int i = t; i < WW * BXH; i += 1024) {
        const int w = i >> 7, ix = i & (BXH - 1);
        gxl[w * (BXH + 1) + ix] = ws[GXOFF + i];
    }

    const int g = t >> 4;                    // replica group 0..63
    const int s = t & 15;                    // uint4 slot within row (8 bins)
    {
        const char* repbase = (const char*)ws + (size_t)REPOFF * 4;
        float a0 = 0.f, a1 = 0.f, a2 = 0.f, a3 = 0.f;
        float a4 = 0.f, a5 = 0.f, a6 = 0.f, a7 = 0.f;
        #pragma unroll 4
        for (int r = g; r < R; r += 64) {
            const uint4 u = *(const uint4*)(repbase + (size_t)r * (REPSZ * 2)
                                            + (size_t)(rowi * 16 + s) * 16);
            a0 += __uint_as_float(u.x << 16);
            a1 += __uint_as_float(u.x & 0xFFFF0000u);
            a2 += __uint_as_float(u.y << 16);
            a3 += __uint_as_float(u.y & 0xFFFF0000u);
            a4 += __uint_as_float(u.z << 16);
            a5 += __uint_as_float(u.z & 0xFFFF0000u);
            a6 += __uint_as_float(u.w << 16);
            a7 += __uint_as_float(u.w & 0xFFFF0000u);
        }
        float4* p4 = (float4*)(part + g * BXH + s * 8);
        p4[0] = make_float4(a0, a1, a2, a3);
        p4[1] = make_float4(a4, a5, a6, a7);
    }
    __syncthreads();

    if (t < BXH) {
        float sum = 0.0f;
        #pragma unroll
        for (int k = 0; k < 64; ++k) sum += part[k * BXH + t];
        row[t] = sum;
    }
    __syncthreads();

    if (t < WW) {
        float acc = 0.0f;
        #pragma unroll 4
        for (int k = 0; k < BXH; ++k)
            acc += row[k] * gxl[t * (BXH + 1) + k];
        ws[POFF + rowi * WW + t] = acc;
    }
    __threadfence();                         // release P row before ticket
    __syncthreads();
    if (t == 0) {
        const int old = atomicAdd((int*)ws + CNTOFF, 1);
        is_last = (old == BYH - 1);
    }
    __syncthreads();
    if (!is_last) return;
    __threadfence();                         // acquire all P rows

    // ---- epilogue: img = gy (50x96) x P (96x50), in LDS ----
    for (int i = t; i < BYH * WW; i += 1024) Pl[i]  = ws[POFF + i];
    for (int i = t; i < HH * BYH; i += 1024) gyl[i] = ws[GYOFF + i];
    __syncthreads();

    if (t < 800) {                           // 50 w-cols x 16 r-chunks of 6
        const int w = t >> 4, rc = t & 15;
        const int r0 = rc * 6;
        const float p0 = Pl[(r0 + 0) * WW + w];
        const float p1 = Pl[(r0 + 1) * WW + w];
        const float p2 = Pl[(r0 + 2) * WW + w];
        const float p3 = Pl[(r0 + 3) * WW + w];
        const float p4 = Pl[(r0 + 4) * WW + w];
        const float p5 = Pl[(r0 + 5) * WW + w];
        for (int h = 0; h < HH; ++h) {
            const float* gyr = gyl + h * BYH + r0;
            float acc = gyr[0] * p0 + gyr[1] * p1 + gyr[2] * p2
                      + gyr[3] * p3 + gyr[4] * p4 + gyr[5] * p5;
            acc += __shfl_xor(acc, 1, 16);
            acc += __shfl_xor(acc, 2, 16);
            acc += __shfl_xor(acc, 4, 16);
            acc += __shfl_xor(acc, 8, 16);
            if (rc == 0) imgl[h * WW + w] = acc;
        }
    }
    __syncthreads();

    float m = -1e30f;
    for (int i = t; i < HH * WW; i += 1024) m = fmaxf(m, imgl[i]);
    #pragma unroll
    for (int off = 32; off > 0; off >>= 1)
        m = fmaxf(m, __shfl_down(m, off));
    if ((t & 63) == 0) redmax[t >> 6] = m;
    __syncthreads();
    if (t == 0) {
        float mm = redmax[0];
        #pragma unroll
        for (int k = 1; k < 16; ++k) mm = fmaxf(mm, redmax[k]);
        redmax[0] = mm;
    }
    __syncthreads();

    const float inv = 1.0f / (redmax[0] + EPSF);
    for (int i = t; i < HH * WW; i += 1024) out[i] = imgl[i] * inv;
}

// ---------------------------------------------------------------------------
extern "C" void kernel_launch(void* const* d_in, const int* in_sizes, int n_in,
                              void* d_out, int out_size, void* d_ws, size_t ws_size,
                              hipStream_t stream) {
    const float4* pairs4 = (const float4*)d_in[0];
    const float*  sigma  = (const float*)d_in[1];
    const float*  grid_x = (const float*)d_in[2];
    const float*  grid_y = (const float*)d_in[3];
    float* ws  = (float*)d_ws;
    float* out = (float*)d_out;
    const int n = in_sizes[0] / 2;

    // replica count from available workspace (bf16 replicas: 24 KB each)
    const long avail_bytes = (long)ws_size - (long)REPOFF * 4;
    long cap = avail_bytes / (REPSZ * 2);
    int R = (int)(cap < 256 ? cap : 256);
    if (R < 1) R = 1;

    pie_hist_lds<<<R, 1024, 0, stream>>>(pairs4, n, grid_x, grid_y, sigma, ws, R);
    pie_c1<<<BYH, 1024, 0, stream>>>(ws, out, R);
}

// Round 5
// 94.982 us; speedup vs baseline: 1.3026x; 1.3026x over previous
//
#include <hip/hip_runtime.h>

#define HH 50
#define WW 50
#define EPSF 1e-8f

// Histogram: x (birth) in [0,1] -> 128 bins; y (pers) in [-0.5, 1.0] -> 96 bins.
// Nearest-bin splat (1 LDS atomic/point). p < -0.5 dropped: gy <= exp(-12.5).
// R4: REVERT to R2's verified 3-kernel structure (96.9 us). R3's fused
//     ticket-epilogue regressed to 47 us: 1536 wave-level __threadfence()
//     (buffer_wbl2/inv L2 sweeps + vmcnt(0)) serialized, kernel 99% stalled.
//     Only change vs R2: K3 release fence hoisted to t==0 after
//     __syncthreads() (syncthreads drains vmcnt -> stores already in L2;
//     one wbl2 flushes the XCD L2). Bit-identical output.
#define BXH 128
#define BYH 96
#define Y0F (-0.5f)
#define YSPAN 1.5f
#define REPSZ (BXH * BYH)            // 12288 bins; LDS 48 KB; bf16 replica 24 KB

// ws float offsets
#define GXOFF 0                       // gx_tab[w][ix] : 50*128 = 6400
#define GYOFF (GXOFF + WW * BXH)      // gy_tab[h][iy] : 50*96  = 4800
#define POFF  (GYOFF + HH * BYH)      // P[iy][w]      : 96*50  = 4800
#define IMGOFF (POFF + BYH * WW)      // img           : 2500
#define CNTOFF (IMGOFF + HH * WW + 12) // int ticket counter (padded)
#define REPOFF (CNTOFF + 4)           // byte offset REPOFF*4 is 16B-aligned
// check: REPOFF = 6400+4800+4800+2500+12+4 = 18516; *4 = 74064 = 16*4629  ok

__device__ __forceinline__ unsigned bf16pk(float a, float b) {
    unsigned ua = __float_as_uint(a), ub = __float_as_uint(b);
    ua = (ua + 0x7FFFu + ((ua >> 16) & 1u)) >> 16;       // RNE
    ub = (ub + 0x7FFFu + ((ub >> 16) & 1u)) >> 16;
    return ua | (ub << 16);
}

__device__ __forceinline__ void splat1(float b, float death, float* hist) {
    const float p = death - b;               // pers == weight (may be negative)
    if (p < Y0F) return;
    int ix = (int)(b * (float)BXH);          // b >= 0: trunc == floor
    int iy = (int)((p - Y0F) * 64.0f);       // BYH/YSPAN = 96/1.5 = 64 exact
    ix = min(ix, BXH - 1);
    iy = min(iy, BYH - 1);
    atomicAdd(&hist[iy * BXH + ix], p);
}

// ---------------------------------------------------------------------------
// K1: per-block private LDS histogram (nearest splat), dump replica as bf16.
// Block 0 additionally builds the exp lookup tables + zeroes the K3 ticket.
// NOTE: do NOT fuse stages behind intra-kernel barriers/fences at scale —
// R3 lesson: 1536 wave-fences (wbl2/inv) serialized into a 47 us stall.
// ---------------------------------------------------------------------------
__global__ __launch_bounds__(1024) void pie_hist_lds(
    const float4* __restrict__ pairs4, int n,
    const float* __restrict__ grid_x, const float* __restrict__ grid_y,
    const float* __restrict__ sigma_p, float* __restrict__ ws, int R)
{
    __shared__ float hist[REPSZ];            // 48 KB
    const int t = threadIdx.x;

    {   // vectorized LDS zero (ds_write_b128): 12288/4/1024 = 3 iters
        const float4 z = make_float4(0.f, 0.f, 0.f, 0.f);
        float4* h4 = (float4*)hist;
        #pragma unroll
        for (int i = t; i < REPSZ / 4; i += 1024) h4[i] = z;
    }

    if (blockIdx.x == 0) {
        if (t == 0) ((int*)ws)[CNTOFF] = 0;  // K3 ticket
        const float s = *sigma_p;
        const float a = 1.0f / (2.0f * s * s);
        for (int i = t; i < WW * BXH; i += 1024) {
            const int w = i >> 7, ix = i & (BXH - 1);
            const float c = (ix + 0.5f) * (1.0f / BXH);
            const float d = grid_x[w] - c;
            ws[GXOFF + i] = __expf(-d * d * a);
        }
        for (int i = t; i < HH * BYH; i += 1024) {
            const int h = i / BYH, iy = i - h * BYH;
            const float c = Y0F + (iy + 0.5f) * (YSPAN / (float)BYH);
            const float d = grid_y[h] - c;
            ws[GYOFF + i] = __expf(-d * d * a);
        }
    }
    __syncthreads();

    const int n2 = n >> 1;                   // two points per float4
    const int stride = R * 1024;
    #pragma unroll 4
    for (int i = blockIdx.x * 1024 + t; i < n2; i += stride) {
        const float4 q = pairs4[i];
        splat1(q.x, q.y, hist);
        splat1(q.z, q.w, hist);
    }
    if ((n & 1) && blockIdx.x == 0 && t == 0) {
        const float2 last = ((const float2*)pairs4)[n - 1];
        splat1(last.x, last.y, hist);
    }
    __syncthreads();

    // dump as bf16: 2x ds_read_b128 -> 1x global_store_dwordx4 (8 bins/iter)
    uint4* dst = (uint4*)((char*)ws + (size_t)REPOFF * 4 + (size_t)blockIdx.x * (REPSZ * 2));
    const float4* src = (const float4*)hist;
    #pragma unroll
    for (int i = t; i < REPSZ / 8; i += 1024) {
        const float4 a = src[2 * i], b = src[2 * i + 1];
        uint4 o;
        o.x = bf16pk(a.x, a.y); o.y = bf16pk(a.z, a.w);
        o.z = bf16pk(b.x, b.y); o.w = bf16pk(b.z, b.w);
        dst[i] = o;
    }
}

// ---------------------------------------------------------------------------
// K2: one block per y-row. Merge R bf16 replicas for this row (uint4 = 8 bins
// per load), then P[row][w] = sum_ix row[ix] * gx_tab[w][ix].
// 640 threads: 40 replica-groups x 16 uint4 slots (16*8 = 128 bins = row).
// ---------------------------------------------------------------------------
__global__ __launch_bounds__(640) void pie_c1(float* __restrict__ ws, int R)
{
    __shared__ float part[40 * BXH];         // 20 KB
    __shared__ float row[BXH];
    __shared__ float gxl[WW * (BXH + 1)];    // stride 129: conflict-free dot
    const int t = threadIdx.x;
    const int rowi = blockIdx.x;

    for (int i = t; i < WW * BXH; i += 640) {
        const int w = i >> 7, ix = i & (BXH - 1);
        gxl[w * (BXH + 1) + ix] = ws[GXOFF + i];
    }

    const int g = t >> 4;                    // replica group 0..39
    const int s = t & 15;                    // uint4 slot within row (8 bins)
    {
        const char* repbase = (const char*)ws + (size_t)REPOFF * 4;
        float a0 = 0.f, a1 = 0.f, a2 = 0.f, a3 = 0.f;
        float a4 = 0.f, a5 = 0.f, a6 = 0.f, a7 = 0.f;
        #pragma unroll 4
        for (int r = g; r < R; r += 40) {
            const uint4 u = *(const uint4*)(repbase + (size_t)r * (REPSZ * 2)
                                            + (size_t)(rowi * 16 + s) * 16);
            a0 += __uint_as_float(u.x << 16);
            a1 += __uint_as_float(u.x & 0xFFFF0000u);
            a2 += __uint_as_float(u.y << 16);
            a3 += __uint_as_float(u.y & 0xFFFF0000u);
            a4 += __uint_as_float(u.z << 16);
            a5 += __uint_as_float(u.z & 0xFFFF0000u);
            a6 += __uint_as_float(u.w << 16);
            a7 += __uint_as_float(u.w & 0xFFFF0000u);
        }
        float4* p4 = (float4*)(part + g * BXH + s * 8);
        p4[0] = make_float4(a0, a1, a2, a3);
        p4[1] = make_float4(a4, a5, a6, a7);
    }
    __syncthreads();

    if (t < BXH) {
        float sum = 0.0f;
        #pragma unroll
        for (int k = 0; k < 40; ++k) sum += part[k * BXH + t];
        row[t] = sum;
    }
    __syncthreads();

    if (t < WW) {
        float acc = 0.0f;
        #pragma unroll 4
        for (int k = 0; k < BXH; ++k)
            acc += row[k] * gxl[t * (BXH + 1) + k];
        ws[POFF + rowi * WW + t] = acc;
    }
}

// ---------------------------------------------------------------------------
// K3: 50 blocks, block h: img[h][w] = sum_r gy[h][r] * P[r][w].
// Last-done block (device atomic ticket) computes max + normalize + writes out.
// Release fence: __syncthreads() drains vmcnt (stores in this XCD's L2),
// then ONE thread's __threadfence() (buffer_wbl2) publishes them. R3 lesson:
// per-wave fences at scale serialize catastrophically — keep fence count low.
// ---------------------------------------------------------------------------
__global__ __launch_bounds__(256) void pie_c2(float* __restrict__ ws,
                                              float* __restrict__ out)
{
    __shared__ float part[4 * WW];
    __shared__ float redmax[4];
    __shared__ int is_last;
    const int h = blockIdx.x;
    const int t = threadIdx.x;

    if (t < 4 * WW) {
        const int w = t % WW;
        const int c = t / WW;                // 0..3, 24 rows each
        const float* gy = ws + GYOFF + h * BYH;
        const float* P  = ws + POFF;
        const int r0 = c * (BYH / 4);
        float acc = 0.0f;
        #pragma unroll 4
        for (int r = r0; r < r0 + BYH / 4; ++r)
            acc += gy[r] * P[r * WW + w];
        part[t] = acc;
    }
    __syncthreads();
    if (t < WW)
        ws[IMGOFF + h * WW + t] = part[t] + part[WW + t] + part[2 * WW + t]
                                + part[3 * WW + t];
    __syncthreads();                         // drains vmcnt: img row is in L2
    if (t == 0) {
        __threadfence();                     // single wbl2: publish img row
        const int old = atomicAdd((int*)ws + CNTOFF, 1);
        is_last = (old == HH - 1);
    }
    __syncthreads();
    if (!is_last) return;
    __threadfence();                         // acquire all img rows (1 block)

    float m = -1e30f;
    for (int i = t; i < HH * WW; i += 256) m = fmaxf(m, ws[IMGOFF + i]);
    #pragma unroll
    for (int off = 32; off > 0; off >>= 1)
        m = fmaxf(m, __shfl_down(m, off));
    const int wv = t >> 6, ln = t & 63;
    if (ln == 0) redmax[wv] = m;
    __syncthreads();
    if (t == 0)
        redmax[0] = fmaxf(fmaxf(redmax[0], redmax[1]), fmaxf(redmax[2], redmax[3]));
    __syncthreads();

    const float inv = 1.0f / (redmax[0] + EPSF);
    for (int i = t; i < HH * WW; i += 256) out[i] = ws[IMGOFF + i] * inv;
}

// ---------------------------------------------------------------------------
extern "C" void kernel_launch(void* const* d_in, const int* in_sizes, int n_in,
                              void* d_out, int out_size, void* d_ws, size_t ws_size,
                              hipStream_t stream) {
    const float4* pairs4 = (const float4*)d_in[0];
    const float*  sigma  = (const float*)d_in[1];
    const float*  grid_x = (const float*)d_in[2];
    const float*  grid_y = (const float*)d_in[3];
    float* ws  = (float*)d_ws;
    float* out = (float*)d_out;
    const int n = in_sizes[0] / 2;

    // replica count from available workspace (bf16 replicas: 24 KB each)
    const long avail_bytes = (long)ws_size - (long)REPOFF * 4;
    long cap = avail_bytes / (REPSZ * 2);
    int R = (int)(cap < 256 ? cap : 256);
    if (R < 1) R = 1;

    pie_hist_lds<<<R, 1024, 0, stream>>>(pairs4, n, grid_x, grid_y, sigma, ws, R);
    pie_c1<<<BYH, 640, 0, stream>>>(ws, R);
    pie_c2<<<HH, 256, 0, stream>>>(ws, out);
}